// Round 2
// baseline (361.203 us; speedup 1.0000x reference)
//
#include <hip/hip_runtime.h>

// SSIM on (32,3,512,512) f32. Separable 11-tap Gaussian, row-streaming.
// Block = 256 threads = 256 columns; streams 128 output rows (+10 halo rows).
// Vertical conv kept entirely in registers via 11 rotating accumulators per
// quantity (static indices from the 11-step unroll). One barrier per row.
//
// R2 fix: slots are reset EVERY step after accumulation (not only when
// emitting). Contributions (i,j) target the emission at step t=i+j; before
// this fix, contributions with i+j<10 survived to t=i+j+11 and contaminated
// output rows r0+1..r0+10 of each band (~8% of pixels, mean off by 2.5e-2).

#define TW   256
#define RH   128
#define BUFW 266   // TW + 10 halo columns

__global__ __launch_bounds__(256) void ssim_main(
    const float* __restrict__ x,
    const float* __restrict__ y,
    const float* __restrict__ window,
    float* __restrict__ partials)
{
    const int tid = threadIdx.x;
    const int bid = blockIdx.x;
    const int img = bid >> 3;        // 96 planes (n*3+c)
    const int rb  = (bid >> 1) & 3;  // row band (4 x 128)
    const int cb  = bid & 1;         // col band (2 x 256)
    const int r0 = rb * RH;
    const int c0 = cb * TW;
    const int c  = c0 + tid;

    const float* xplane = x + (size_t)img * 262144;
    const float* yplane = y + (size_t)img * 262144;

    // Recover 1-D gaussian: row i of outer(g,g) sums to g_i (since sum(g)=1).
    float g[11];
    #pragma unroll
    for (int ii = 0; ii < 11; ++ii) {
        float s = 0.f;
        #pragma unroll
        for (int jj = 0; jj < 11; ++jj) s += window[ii * 11 + jj];
        g[ii] = s;
    }

    __shared__ float sxbuf[2][BUFW];
    __shared__ float sybuf[2][BUFW];

    float accx[11], accy[11], accxx[11], accyy[11], accxy[11];
    #pragma unroll
    for (int s = 0; s < 11; ++s) {
        accx[s] = 0.f; accy[s] = 0.f; accxx[s] = 0.f; accyy[s] = 0.f; accxy[s] = 0.f;
    }

    // Preload row r0-5 into buffer 0 (zero pad outside image).
    {
        const int rn = r0 - 5;
        float ax = 0.f, ay = 0.f, hxv = 0.f, hyv = 0.f;
        if (rn >= 0) {
            const float* xp = xplane + rn * 512;
            const float* yp = yplane + rn * 512;
            ax = xp[c]; ay = yp[c];
            if (tid < 5) {
                const int ch = c0 - 5 + tid;
                if (ch >= 0) { hxv = xp[ch]; hyv = yp[ch]; }
            } else if (tid < 10) {
                const int ch = c0 + TW + (tid - 5);
                if (ch < 512) { hxv = xp[ch]; hyv = yp[ch]; }
            }
        }
        sxbuf[0][tid + 5] = ax; sybuf[0][tid + 5] = ay;
        if (tid < 5)       { sxbuf[0][tid] = hxv;                 sybuf[0][tid] = hyv; }
        else if (tid < 10) { sxbuf[0][TW + 5 + (tid - 5)] = hxv;  sybuf[0][TW + 5 + (tid - 5)] = hyv; }
    }
    __syncthreads();

    float tsum = 0.f;
    const float C1 = 1e-4f;   // 0.01^2
    const float C2 = 9e-4f;   // 0.03^2

    int cur = 0;
    // 143 steps = 13 chunks x 11 (11-step unroll makes acc slots static).
    for (int chunk = 0; chunk < 13; ++chunk) {
        #pragma unroll
        for (int rr = 0; rr < 11; ++rr) {
            const int i = chunk * 11 + rr;

            // Prefetch next input row r0-4+i (used at end of this step).
            const int rn = r0 - 4 + i;
            float ax = 0.f, ay = 0.f, hxv = 0.f, hyv = 0.f;
            if ((unsigned)rn < 512u) {
                const float* xp = xplane + rn * 512;
                const float* yp = yplane + rn * 512;
                ax = xp[c]; ay = yp[c];
                if (tid < 5) {
                    const int ch = c0 - 5 + tid;
                    if (ch >= 0) { hxv = xp[ch]; hyv = yp[ch]; }
                } else if (tid < 10) {
                    const int ch = c0 + TW + (tid - 5);
                    if (ch < 512) { hxv = xp[ch]; hyv = yp[ch]; }
                }
            }

            // Horizontal 11-tap conv of x, y, x^2, y^2, xy for this thread's col.
            const float* xr = sxbuf[cur];
            const float* yr = sybuf[cur];
            float sx = 0.f, sy = 0.f, sxx = 0.f, syy = 0.f, sxy = 0.f;
            #pragma unroll
            for (int j = 0; j < 11; ++j) {
                const float xv = xr[tid + j];
                const float yv = yr[tid + j];
                const float t1 = g[j] * xv;
                const float t2 = g[j] * yv;
                sx += t1; sy += t2;
                sxx = fmaf(t1, xv, sxx);
                syy = fmaf(t2, yv, syy);
                sxy = fmaf(t1, yv, sxy);
            }

            // Vertical accumulate into rotating slots (static indices).
            #pragma unroll
            for (int j = 0; j < 11; ++j) {
                const int s = (rr + j) % 11;
                const float wv = g[10 - j];
                accx[s]  = fmaf(wv, sx,  accx[s]);
                accy[s]  = fmaf(wv, sy,  accy[s]);
                accxx[s] = fmaf(wv, sxx, accxx[s]);
                accyy[s] = fmaf(wv, syy, accyy[s]);
                accxy[s] = fmaf(wv, sxy, accxy[s]);
            }

            // Emit completed output row (slot = i % 11 = rr); uniform branch.
            {
                const int s = rr;
                if (i >= 10 && i < 10 + RH) {
                    const float mux = accx[s], muy = accy[s];
                    const float mux2 = mux * mux, muy2 = muy * muy, muxy = mux * muy;
                    const float vx  = accxx[s] - mux2;
                    const float vy  = accyy[s] - muy2;
                    const float vxy = accxy[s] - muxy;
                    const float num = fmaf(2.f, muxy, C1) * fmaf(2.f, vxy, C2);
                    const float den = (mux2 + muy2 + C1) * (vx + vy + C2);
                    tsum += num / den;
                }
                // Reset EVERY step: steps i<10 discard partial sums that would
                // otherwise contaminate the first 10 emitted rows (R2 fix).
                accx[s] = 0.f; accy[s] = 0.f; accxx[s] = 0.f; accyy[s] = 0.f; accxy[s] = 0.f;
            }

            // Store prefetched row into the other buffer; single barrier/step.
            const int nxt = cur ^ 1;
            sxbuf[nxt][tid + 5] = ax; sybuf[nxt][tid + 5] = ay;
            if (tid < 5)       { sxbuf[nxt][tid] = hxv;                sybuf[nxt][tid] = hyv; }
            else if (tid < 10) { sxbuf[nxt][TW + 5 + (tid - 5)] = hxv; sybuf[nxt][TW + 5 + (tid - 5)] = hyv; }
            __syncthreads();
            cur = nxt;
        }
    }

    // Block reduction: wave shuffle then LDS across the 4 waves.
    #pragma unroll
    for (int off = 32; off > 0; off >>= 1)
        tsum += __shfl_down(tsum, off, 64);
    __shared__ float wsum[4];
    if ((tid & 63) == 0) wsum[tid >> 6] = tsum;
    __syncthreads();
    if (tid == 0)
        partials[bid] = (wsum[0] + wsum[1]) + (wsum[2] + wsum[3]);
}

__global__ __launch_bounds__(256) void ssim_reduce(
    const float* __restrict__ partials, float* __restrict__ out, int n)
{
    const int tid = threadIdx.x;
    double s = 0.0;
    for (int idx = tid; idx < n; idx += 256) s += (double)partials[idx];
    #pragma unroll
    for (int off = 32; off > 0; off >>= 1)
        s += __shfl_down(s, off, 64);
    __shared__ double ws[4];
    if ((tid & 63) == 0) ws[tid >> 6] = s;
    __syncthreads();
    if (tid == 0)
        out[0] = (float)((ws[0] + ws[1] + ws[2] + ws[3]) / 25165824.0);
}

extern "C" void kernel_launch(void* const* d_in, const int* in_sizes, int n_in,
                              void* d_out, int out_size, void* d_ws, size_t ws_size,
                              hipStream_t stream)
{
    const float* x = (const float*)d_in[0];
    const float* y = (const float*)d_in[1];
    const float* w = (const float*)d_in[2];
    float* partials = (float*)d_ws;   // 768 floats

    // 96 planes x 2 col-bands x 4 row-bands = 768 blocks
    ssim_main<<<768, 256, 0, stream>>>(x, y, w, partials);
    ssim_reduce<<<1, 256, 0, stream>>>(partials, (float*)d_out, 768);
}